// Round 5
// baseline (5241.082 us; speedup 1.0000x reference)
//
#include <hip/hip_runtime.h>
#include <math.h>

// NeuralTPP: B=4096, L=512, H=HH=32.
// Lane i of each 32-lane group owns hidden unit i; 2 batch elems per wave64.
// - Weights packed float4 [j][i] in LDS: ONE ds_read_b128 per j (broadcast
//   across the two wave halves, conflict-free).
// - h broadcast: 1 ds_write + 16 uniform float2 reads per step (no swizzles).
// - Intensity (tanh + dual 32-lane reduction + store) DEFERRED in register
//   batches of 8 steps: 8 independent butterfly chains -> swizzle latency
//   hidden by ILP, and off the recurrence critical path.
// - Phase 2 (softplus/log/sigmoid over stored raw/v2) unchanged.

constexpr int Bn = 4096;
constexpr int Ln = 512;
constexpr int Hn = 32;
constexpr float EPSf = 1e-8f;

__device__ __forceinline__ float sigmoidf_(float x) {
    return __fdividef(1.0f, 1.0f + __expf(-x));
}
__device__ __forceinline__ float tanhf_(float x) {
    x = fminf(x, 15.0f);
    const float e = __expf(2.0f * x);
    return __fdividef(e - 1.0f, e + 1.0f);
}
__device__ __forceinline__ float softplusf_(float x) {
    return fmaxf(x, 0.0f) + __logf(1.0f + __expf(-fabsf(x)));
}

template <int IMM>
__device__ __forceinline__ float swz(float v) {
    return __int_as_float(__builtin_amdgcn_ds_swizzle(__float_as_int(v), IMM));
}

__global__ __launch_bounds__(256, 2)
void tpp_main(const float* __restrict__ deltas,
              const float* __restrict__ mask,
              const float* __restrict__ w_ih,
              const float* __restrict__ w_hh,
              const float* __restrict__ b_ih,
              const float* __restrict__ b_hh,
              const float* __restrict__ w1,
              const float* __restrict__ b1,
              const float* __restrict__ w2,
              const float* __restrict__ b2,
              float* __restrict__ partials)   // [2 * gridDim.x]
{
    const int tid = threadIdx.x;
    const int grp = tid >> 5;            // 0..7
    const int i   = tid & 31;            // hidden unit
    const int b   = blockIdx.x * 8 + grp;

    __shared__ float4 wq[Hn][Hn];        // [j][i]={whr,whz,whn,w1h}  16 KiB
    __shared__ float  hbuf[8][Hn];       // per-group h               1 KiB
    __shared__ float  buf[8 * Ln * 2];   // [grp][t][{raw,v2}]        32 KiB

    // ---- stage packed weights (transpose on the fly), once ----
    for (int k = tid; k < Hn * Hn; k += 256) {
        const int j = k >> 5, ii = k & 31;
        wq[j][ii] = make_float4(w_hh[ii * Hn + j],
                                w_hh[(Hn + ii) * Hn + j],
                                w_hh[(2 * Hn + ii) * Hn + j],
                                w1[ii * (Hn + 1) + 1 + j]);
    }

    const float wihr = w_ih[i], wihz = w_ih[Hn + i], wihn = w_ih[2 * Hn + i];
    const float bihn = b_ih[2 * Hn + i];
    const float br = b_ih[i] + b_hh[i];
    const float bz = b_ih[Hn + i] + b_hh[Hn + i];
    const float bhn = b_hh[2 * Hn + i];
    const float w1t = w1[i * (Hn + 1)];
    const float b1i = b1[i];
    const float w2i = w2[i];
    const float ci  = w1t * w2i;
    const float b2v = b2[0];

    const float* dp = deltas + (size_t)b * Ln;
    const float* mp = mask   + (size_t)b * Ln;

    float h = 0.0f;

    // current / next 8-step input blocks (float4 pairs, statically indexed)
    float4 tc0 = *(const float4*)(dp);
    float4 tc1 = *(const float4*)(dp + 4);
    float4 mc0 = *(const float4*)(mp);
    float4 mc1 = *(const float4*)(mp + 4);

    __syncthreads();

    for (int tb = 0; tb < Ln; tb += 8) {
        const int tnb = (tb + 8 < Ln) ? (tb + 8) : 0;   // clamped prefetch
        const float4 tn0 = *(const float4*)(dp + tnb);
        const float4 tn1 = *(const float4*)(dp + tnb + 4);
        const float4 mn0 = *(const float4*)(mp + tnb);
        const float4 mn1 = *(const float4*)(mp + tnb + 4);

        float pre_s[8];

#define STEP(S, TAU, MM)                                                    \
        {                                                                   \
            const float tau = (TAU);                                        \
            const float m   = (MM);                                         \
            hbuf[grp][i] = h;                                               \
            float hr = br, hz = bz, hn = bhn;                               \
            float pre = fmaf(tau, w1t, b1i);                                \
            _Pragma("unroll")                                               \
            for (int jj = 0; jj < Hn; jj += 2) {                            \
                const float2 hp = *(const float2*)&hbuf[grp][jj];           \
                const float4 w0 = wq[jj][i];                                \
                const float4 w1q = wq[jj + 1][i];                           \
                hr  = fmaf(w0.x, hp.x, hr);                                 \
                hz  = fmaf(w0.y, hp.x, hz);                                 \
                hn  = fmaf(w0.z, hp.x, hn);                                 \
                pre = fmaf(w0.w, hp.x, pre);                                \
                hr  = fmaf(w1q.x, hp.y, hr);                                \
                hz  = fmaf(w1q.y, hp.y, hz);                                \
                hn  = fmaf(w1q.z, hp.y, hn);                                \
                pre = fmaf(w1q.w, hp.y, pre);                               \
            }                                                               \
            pre_s[S] = pre;                                                 \
            const float r = sigmoidf_(fmaf(tau, wihr, hr));                 \
            const float z = sigmoidf_(fmaf(tau, wihz, hz));                 \
            const float n = tanhf_(fmaf(r, hn, fmaf(tau, wihn, bihn)));     \
            h = fmaf(m, fmaf(z, h - n, n) - h, h);                          \
        }

        STEP(0, tc0.x, mc0.x)
        STEP(1, tc0.y, mc0.y)
        STEP(2, tc0.z, mc0.z)
        STEP(3, tc0.w, mc0.w)
        STEP(4, tc1.x, mc1.x)
        STEP(5, tc1.y, mc1.y)
        STEP(6, tc1.z, mc1.z)
        STEP(7, tc1.w, mc1.w)
#undef STEP

        // ---- deferred intensity for the 8 steps (independent chains) ----
        float sv[8];
#pragma unroll
        for (int s = 0; s < 8; ++s) {
            const float a  = tanhf_(pre_s[s]);
            const float v1 = a * w2i;
            const float v2 = fmaf(a * a, -ci, ci);     // (1-a^2)*w1t*w2
            const float t1 = swz<((1 << 10) | 0x1f)>(v1);
            const float t2 = swz<((1 << 10) | 0x1f)>(v2);
            sv[s] = (i & 1) ? (v2 + t2) : (v1 + t1);
        }
#pragma unroll
        for (int s = 0; s < 8; ++s) sv[s] += swz<((2 << 10) | 0x1f)>(sv[s]);
#pragma unroll
        for (int s = 0; s < 8; ++s) sv[s] += swz<((4 << 10) | 0x1f)>(sv[s]);
#pragma unroll
        for (int s = 0; s < 8; ++s) sv[s] += swz<((8 << 10) | 0x1f)>(sv[s]);
#pragma unroll
        for (int s = 0; s < 8; ++s) sv[s] += swz<((16 << 10) | 0x1f)>(sv[s]);

        // lane 2k -> raw of step tb+k, lane 2k+1 -> v2 of step tb+k
        {
            const float o01 = (i & 2) ? sv[1] : sv[0];
            const float o23 = (i & 2) ? sv[3] : sv[2];
            const float o45 = (i & 2) ? sv[5] : sv[4];
            const float o67 = (i & 2) ? sv[7] : sv[6];
            const float oa  = (i & 4) ? o23 : o01;
            const float ob  = (i & 4) ? o67 : o45;
            const float out = (i & 8) ? ob : oa;
            if (i < 16)
                buf[(grp << 10) + ((tb + (i >> 1)) << 1) + (i & 1)] =
                    (i & 1) ? out : (out + b2v);
        }

        tc0 = tn0; tc1 = tn1; mc0 = mn0; mc1 = mn1;
    }

    __syncthreads();

    // ---- phase 2: LL transcendentals, all 256 lanes useful ----
    const float* mblk = mask + (size_t)blockIdx.x * 8 * Ln;
    float T = 0.0f, M = 0.0f;
#pragma unroll
    for (int k = 0; k < 16; ++k) {
        const int idx = (k << 8) + tid;            // 0..4095 over [grp][t]
        const float raw = buf[idx * 2];
        const float v2  = buf[idx * 2 + 1];
        const float mm  = mblk[idx];
        const float phi  = softplusf_(raw);
        const float dphi = sigmoidf_(raw) * v2;
        const float lam  = softplusf_(dphi) + EPSf;
        T = fmaf(__logf(lam) - phi, mm, T);
        M += mm;
    }
#pragma unroll
    for (int d = 1; d < 64; d <<= 1) {
        T += __shfl_xor(T, d, 64);
        M += __shfl_xor(M, d, 64);
    }
    __shared__ float sT[4], sM[4];
    const int w = tid >> 6;
    if ((tid & 63) == 0) { sT[w] = T; sM[w] = M; }
    __syncthreads();
    if (tid == 0) {
        partials[blockIdx.x]             = sT[0] + sT[1] + sT[2] + sT[3];
        partials[gridDim.x + blockIdx.x] = sM[0] + sM[1] + sM[2] + sM[3];
    }
}

__global__ __launch_bounds__(256)
void tpp_final(const float* __restrict__ partials, int nparts,
               float* __restrict__ out)
{
    const int tid = threadIdx.x;
    double T = 0.0, M = 0.0;
    for (int k = tid; k < nparts; k += 256) {
        T += (double)partials[k];
        M += (double)partials[nparts + k];
    }
#pragma unroll
    for (int d = 1; d < 64; d <<= 1) {
        T += __shfl_xor(T, d, 64);
        M += __shfl_xor(M, d, 64);
    }
    __shared__ double sT[4], sM[4];
    const int w = tid >> 6;
    if ((tid & 63) == 0) { sT[w] = T; sM[w] = M; }
    __syncthreads();
    if (tid == 0) {
        const double t2 = sT[0] + sT[1] + sT[2] + sT[3];
        const double m2 = sM[0] + sM[1] + sM[2] + sM[3];
        out[0] = (float)(t2 / (m2 + (double)EPSf));
    }
}

extern "C" void kernel_launch(void* const* d_in, const int* in_sizes, int n_in,
                              void* d_out, int out_size, void* d_ws, size_t ws_size,
                              hipStream_t stream) {
    const float* deltas = (const float*)d_in[0];
    const float* mask   = (const float*)d_in[1];
    const float* w_ih   = (const float*)d_in[2];
    const float* w_hh   = (const float*)d_in[3];
    const float* b_ih   = (const float*)d_in[4];
    const float* b_hh   = (const float*)d_in[5];
    const float* w1     = (const float*)d_in[6];
    const float* b1     = (const float*)d_in[7];
    const float* w2     = (const float*)d_in[8];
    const float* b2     = (const float*)d_in[9];
    float* out = (float*)d_out;
    float* partials = (float*)d_ws;     // 2 * 512 * 4 B = 4 KiB

    const int nblocks = Bn / 8;         // 512
    tpp_main<<<nblocks, 256, 0, stream>>>(deltas, mask, w_ih, w_hh, b_ih, b_hh,
                                          w1, b1, w2, b2, partials);
    tpp_final<<<1, 256, 0, stream>>>(partials, nblocks, out);
}

// Round 6
// 726.074 us; speedup vs baseline: 7.2184x; 7.2184x over previous
//
#include <hip/hip_runtime.h>
#include <math.h>

// NeuralTPP: B=4096, L=512, H=HH=32 — MFMA formulation.
// One wave (64 thr) per block handles 16 sequences. Per step:
//   C[128,16] = W[128,32] x H[32,16]  as 8x mfma_f32_16x16x32_f16.
// W rows stacked [r(32); z(32); n(32); w1_h(32)], placed into 8 16-row tiles
// with a row permutation chosen so that lane (c=l&15, g=l>>4) reg d of tile
// parity p computes unit u = 8g+4p+d — exactly the B-fragment k-slots
// (k=8g+e, e=4p+d) this lane supplies next step => ZERO cross-lane repack.
// Gates + intensity tanh in fp32 VALU; softplus/log/sigmoid of the two
// per-(b,t) scalars deferred to phase 2 via fp16-packed LDS (32 KB).
// fp16 matvec error ~5e-4/step, stationary drift ~2e-3 << 0.02 threshold.

constexpr int Bn = 4096;
constexpr int Ln = 512;
constexpr float EPSf = 1e-8f;

typedef _Float16 f16x8 __attribute__((ext_vector_type(8)));
typedef float    f32x4 __attribute__((ext_vector_type(4)));

__device__ __forceinline__ float sigmoidf_(float x) {
    return __fdividef(1.0f, 1.0f + __expf(-x));
}
__device__ __forceinline__ float tanhf_(float x) {
    x = fminf(x, 15.0f);
    const float e = __expf(2.0f * x);
    return __fdividef(e - 1.0f, e + 1.0f);
}
__device__ __forceinline__ float softplusf_(float x) {
    return fmaxf(x, 0.0f) + __logf(1.0f + __expf(-fabsf(x)));
}

union PK2 { _Float16 f[2]; unsigned u; };

__global__ __launch_bounds__(64, 1)
void tpp_main(const float* __restrict__ deltas,
              const float* __restrict__ mask,
              const float* __restrict__ w_ih,
              const float* __restrict__ w_hh,
              const float* __restrict__ b_ih,
              const float* __restrict__ b_hh,
              const float* __restrict__ w1,
              const float* __restrict__ b1,
              const float* __restrict__ w2,
              const float* __restrict__ b2,
              float* __restrict__ partials)   // [2 * gridDim.x]
{
    const int l  = threadIdx.x;          // 0..63
    const int c  = l & 15;               // batch column
    const int g  = l >> 4;               // 0..3 (k-group / row-group)
    const int b0 = blockIdx.x * 16;

    __shared__ unsigned buf[16][Ln];     // fp16-packed (raw, v2s) = 32 KiB

    // ---- A fragments: 8 tiles (r0,r1,z0,z1,n0,n1,p0,p1), fp16, registers ----
    // tile T = 2G+p ; row rr = l&15 -> unit u = 8*(rr>>2) + 4p + (rr&3)
    // k-cols j = 8*(l>>4) + e
    f16x8 Af[8];
    {
        const int rr = c;
        const int j0 = 8 * g;
#pragma unroll
        for (int T = 0; T < 8; ++T) {
            const int G = T >> 1, p = T & 1;
            const int u = 8 * (rr >> 2) + 4 * p + (rr & 3);
            const float* src =
                (G == 0) ? (w_hh + (size_t)u * 32 + j0) :
                (G == 1) ? (w_hh + (size_t)(32 + u) * 32 + j0) :
                (G == 2) ? (w_hh + (size_t)(64 + u) * 32 + j0) :
                           (w1   + (size_t)u * 33 + 1 + j0);
#pragma unroll
            for (int e = 0; e < 8; ++e) Af[T][e] = (_Float16)src[e];
        }
    }

    // ---- per-unit scalars for this lane's 8 units u = 8g + e ----
    float wihr[8], wihz[8], wihn[8], br[8], bz[8], bin[8], bhn[8];
    float w1t[8], b1v[8], w2v[8], civ[8];
#pragma unroll
    for (int e = 0; e < 8; ++e) {
        const int u = 8 * g + e;
        wihr[e] = w_ih[u];
        wihz[e] = w_ih[32 + u];
        wihn[e] = w_ih[64 + u];
        br[e]   = b_ih[u]      + b_hh[u];
        bz[e]   = b_ih[32 + u] + b_hh[32 + u];
        bin[e]  = b_ih[64 + u];
        bhn[e]  = b_hh[64 + u];
        w1t[e]  = w1[(size_t)u * 33];
        b1v[e]  = b1[u];
        w2v[e]  = w2[u];
        civ[e]  = w1t[e] * w2v[e];
    }
    const float b2v = b2[0];

    const float* dp0 = deltas + (size_t)(b0 + c) * Ln;
    const float* mp0 = mask   + (size_t)(b0 + c) * Ln;

    float hreg[8];
#pragma unroll
    for (int e = 0; e < 8; ++e) hreg[e] = 0.0f;

    float tau = dp0[0];
    float m   = mp0[0];

    const f32x4 z4 = {0.0f, 0.0f, 0.0f, 0.0f};

    for (int t = 0; t < Ln; ++t) {
        const int tn = (t + 1 < Ln) ? (t + 1) : (Ln - 1);
        const float tau_n = dp0[tn];
        const float m_n   = mp0[tn];

        // ---- B fragment from own h (k = 8g+e) ----
        f16x8 bf;
#pragma unroll
        for (int e = 0; e < 8; ++e) bf[e] = (_Float16)hreg[e];

        // ---- 8 MFMAs: all four gate blocks ----
        f32x4 acc[8];
#pragma unroll
        for (int T = 0; T < 8; ++T)
            acc[T] = __builtin_amdgcn_mfma_f32_16x16x32_f16(Af[T], bf, z4, 0, 0, 0);

        // ---- gates + intensity partials, 8 units/lane ----
        float v1p = 0.0f, v2p = 0.0f;
#pragma unroll
        for (int p = 0; p < 2; ++p) {
#pragma unroll
            for (int d = 0; d < 4; ++d) {
                const int e = 4 * p + d;
                const float gr = acc[0 + p][d];
                const float gz = acc[2 + p][d];
                const float gn = acc[4 + p][d];
                const float gp = acc[6 + p][d];
                const float r  = sigmoidf_(fmaf(tau, wihr[e], br[e]) + gr);
                const float zz = sigmoidf_(fmaf(tau, wihz[e], bz[e]) + gz);
                const float nn = tanhf_(fmaf(tau, wihn[e], bin[e]) + r * (gn + bhn[e]));
                const float pre = gp + fmaf(tau, w1t[e], b1v[e]);
                const float a   = tanhf_(pre);
                v1p = fmaf(a, w2v[e], v1p);
                v2p = fmaf(a * a, -civ[e], v2p + civ[e]);
                const float hn2 = nn + zz * (hreg[e] - nn);
                hreg[e] = fmaf(m, hn2 - hreg[e], hreg[e]);
            }
        }

        // ---- reduce over g (4 lanes per column): xor16 + xor32 ----
        v1p += __shfl_xor(v1p, 16, 64);
        v1p += __shfl_xor(v1p, 32, 64);
        v2p += __shfl_xor(v2p, 16, 64);
        v2p += __shfl_xor(v2p, 32, 64);

        if (l < 16) {
            PK2 pk;
            pk.f[0] = (_Float16)(v1p + b2v);   // raw
            pk.f[1] = (_Float16)v2p;           // v2s
            buf[l][t] = pk.u;
        }

        tau = tau_n;
        m   = m_n;
    }

    __syncthreads();

    // ---- phase 2: LL transcendentals over 16 x 512 items ----
    float T = 0.0f, M = 0.0f;
    for (int it = 0; it < 128; ++it) {
        const int idx = it * 64 + l;        // c*512 + t
        const int cc  = idx >> 9;
        const int tt  = idx & 511;
        PK2 pk; pk.u = buf[cc][tt];
        const float raw = (float)pk.f[0];
        const float v2  = (float)pk.f[1];
        const float mm  = mask[(size_t)(b0 + cc) * Ln + tt];
        const float phi  = softplusf_(raw);
        const float dphi = sigmoidf_(raw) * v2;
        const float lam  = softplusf_(dphi) + EPSf;
        T = fmaf(__logf(lam) - phi, mm, T);
        M += mm;
    }
#pragma unroll
    for (int d = 1; d < 64; d <<= 1) {
        T += __shfl_xor(T, d, 64);
        M += __shfl_xor(M, d, 64);
    }
    if (l == 0) {
        partials[blockIdx.x]             = T;
        partials[gridDim.x + blockIdx.x] = M;
    }
}

__global__ __launch_bounds__(256)
void tpp_final(const float* __restrict__ partials, int nparts,
               float* __restrict__ out)
{
    const int tid = threadIdx.x;
    double T = 0.0, M = 0.0;
    for (int k = tid; k < nparts; k += 256) {
        T += (double)partials[k];
        M += (double)partials[nparts + k];
    }
#pragma unroll
    for (int d = 1; d < 64; d <<= 1) {
        T += __shfl_xor(T, d, 64);
        M += __shfl_xor(M, d, 64);
    }
    __shared__ double sT[4], sM[4];
    const int w = tid >> 6;
    if ((tid & 63) == 0) { sT[w] = T; sM[w] = M; }
    __syncthreads();
    if (tid == 0) {
        const double t2 = sT[0] + sT[1] + sT[2] + sT[3];
        const double m2 = sM[0] + sM[1] + sM[2] + sM[3];
        out[0] = (float)(t2 / (m2 + (double)EPSf));
    }
}

extern "C" void kernel_launch(void* const* d_in, const int* in_sizes, int n_in,
                              void* d_out, int out_size, void* d_ws, size_t ws_size,
                              hipStream_t stream) {
    const float* deltas = (const float*)d_in[0];
    const float* mask   = (const float*)d_in[1];
    const float* w_ih   = (const float*)d_in[2];
    const float* w_hh   = (const float*)d_in[3];
    const float* b_ih   = (const float*)d_in[4];
    const float* b_hh   = (const float*)d_in[5];
    const float* w1     = (const float*)d_in[6];
    const float* b1     = (const float*)d_in[7];
    const float* w2     = (const float*)d_in[8];
    const float* b2     = (const float*)d_in[9];
    float* out = (float*)d_out;
    float* partials = (float*)d_ws;      // 2 * 256 * 4 B

    const int nblocks = Bn / 16;         // 256
    tpp_main<<<nblocks, 64, 0, stream>>>(deltas, mask, w_ih, w_hh, b_ih, b_hh,
                                         w1, b1, w2, b2, partials);
    tpp_final<<<1, 256, 0, stream>>>(partials, nblocks, out);
}